// Round 2
// baseline (184462.476 us; speedup 1.0000x reference)
//
#include <hip/hip_runtime.h>
#include <hip/hip_cooperative_groups.h>
#include <cstdint>
#include <cfloat>
#include <cmath>

namespace cg = cooperative_groups;

#define NB 64
#define LL 2048
#define HH 512
#define VV 34
#define TT 600
#define GRID 256
#define BLKT 512

// JAX threefry_partitionable default (jax >= 0.4.36): bits = o0 ^ o1 of threefry(key,(0,i)).
// Set to 0 for legacy split-half random_bits if tokens mismatch wholesale.
#define PARTITIONABLE 1

__device__ __forceinline__ float sigm_(float x){ return 1.0f/(1.0f+expf(-x)); }
__device__ __forceinline__ unsigned rotl_(unsigned x, int r){ return (x<<r)|(x>>(32-r)); }

// Threefry-2x32, 20 rounds, exactly JAX's schedule.
__device__ __forceinline__ void tf2x32_(unsigned k0, unsigned k1, unsigned x0, unsigned x1,
                                        unsigned &o0, unsigned &o1){
  unsigned ks2 = k0 ^ k1 ^ 0x1BD11BDAu;
  x0 += k0; x1 += k1;
  x0+=x1; x1=rotl_(x1,13); x1^=x0;
  x0+=x1; x1=rotl_(x1,15); x1^=x0;
  x0+=x1; x1=rotl_(x1,26); x1^=x0;
  x0+=x1; x1=rotl_(x1, 6); x1^=x0;
  x0+=k1; x1+=ks2+1u;
  x0+=x1; x1=rotl_(x1,17); x1^=x0;
  x0+=x1; x1=rotl_(x1,29); x1^=x0;
  x0+=x1; x1=rotl_(x1,16); x1^=x0;
  x0+=x1; x1=rotl_(x1,24); x1^=x0;
  x0+=ks2; x1+=k0+2u;
  x0+=x1; x1=rotl_(x1,13); x1^=x0;
  x0+=x1; x1=rotl_(x1,15); x1^=x0;
  x0+=x1; x1=rotl_(x1,26); x1^=x0;
  x0+=x1; x1=rotl_(x1, 6); x1^=x0;
  x0+=k0; x1+=k1+3u;
  x0+=x1; x1=rotl_(x1,17); x1^=x0;
  x0+=x1; x1=rotl_(x1,29); x1^=x0;
  x0+=x1; x1=rotl_(x1,16); x1^=x0;
  x0+=x1; x1=rotl_(x1,24); x1^=x0;
  x0+=k1; x1+=ks2+4u;
  x0+=x1; x1=rotl_(x1,13); x1^=x0;
  x0+=x1; x1=rotl_(x1,15); x1^=x0;
  x0+=x1; x1=rotl_(x1,26); x1^=x0;
  x0+=x1; x1=rotl_(x1, 6); x1^=x0;
  x0+=ks2; x1+=k0+5u;
  o0 = x0; o1 = x1;
}

__global__ __launch_bounds__(BLKT, 2) void speller_kernel(
    const float* __restrict__ seq, const int* __restrict__ slen,
    const float* __restrict__ Ech, const float* __restrict__ Wkey,
    const float* __restrict__ Wval, const float* __restrict__ bval,
    const float* __restrict__ Wih, const float* __restrict__ Whh,
    const float* __restrict__ bih, const float* __restrict__ bhh,
    const float* __restrict__ Wcdn, const float* __restrict__ bcdn,
    int* __restrict__ out, float* __restrict__ ws, int MS, int CH)
{
  cg::grid_group grid = cg::this_grid();
  const int tid = threadIdx.x;
  const int bid = blockIdx.x;
  const int gid = bid*BLKT + tid;

  // ---- workspace layout ----
  float* biasf = ws;                         // [2048]  b_ih + b_hh
  float* h0    = biasf + 2048;               // [NB*HH]
  float* h1    = h0 + NB*HH;                 // [NB*HH]
  float* cb    = h1 + NB*HH;                 // [NB*HH]
  float* ctx   = cb + NB*HH;                 // [NB*HH]   attention context (materialized, like ref)
  float* qt    = ctx + NB*HH;                // [NB*HH]   q~ = Wkey^T h
  float* pm    = qt + NB*HH;                 // [NB*MS]   chunk max
  float* ps    = pm + NB*MS;                 // [NB*MS]   chunk sum
  float* pacc  = ps + NB*MS;                 // [NB*MS*HH] chunk weighted-e accumulators
  int*   iw    = (int*)(pacc + (size_t)NB*MS*HH);
  int*   yv    = iw;                          // [64] prev tokens
  int*   pref  = iw + 64;                     // [65] chunk prefix
  int*   nTotP = iw + 129;
  int*   cntP  = iw + 130;

  __shared__ float sXs[128*65];   // A: transposed X tile (pad 65 vs bank conflicts)
  __shared__ float sRed[8*8*64];  // A: cross-wave partial reduce
  __shared__ float sGate[8*64];   // A: gates
  __shared__ float sAcc[8*512];   // C: per-wave accumulators
  __shared__ float sWm[8], sWs[8], sWf[8];
  __shared__ float sEb[512];      // D: ebar (weighted mean of e)
  __shared__ float sHs[512];      // D: h
  __shared__ float sCt[512];      // D: ctx = Wval*ebar + bval
  __shared__ float sP[34*8];      // D: logit partials
  __shared__ float sZ[34];        // D: logits+gumbel
  __shared__ float sAm[32], sAs[32], sAf[32];
  __shared__ float sSc[2];
  __shared__ int   sChunk;
  __shared__ int   sPref[65];
  __shared__ int   sLenA[64];

  // ================= P0: one-time precompute =================
  {
    if (gid < NB*HH){ h0[gid]=0.f; h1[gid]=0.f; cb[gid]=0.f; qt[gid]=0.f; }
    if (gid < NB) yv[gid] = 0;  // SOS
    if (gid < 2048) biasf[gid] = bih[gid] + bhh[gid];
    if (gid == 0){
      int acc = 0; pref[0] = 0;
      for (int b=0;b<NB;b++){
        int ln = slen[b]; if (ln < 1) ln = 1; if (ln > LL) ln = LL;
        acc += (ln + CH - 1)/CH;
        pref[b+1] = acc;
      }
      *nTotP = acc; *cntP = 0;
    }
  }

  // ================= phase lambdas =================

  // A: gates = Wih*[emb(y); ctx] + Whh*h + biasf ; LSTM update -> c, hw
  auto phaseA = [&](const float* hr, float* hw){
    const int k0 = bid*2;
    const int w = tid >> 6, lane = tid & 63;
    float acc[8];
    #pragma unroll
    for (int jj=0;jj<8;jj++) acc[jj]=0.f;
    for (int kt=0; kt<12; kt++){
      __syncthreads();
      // stage 128x64 transposed X tile
      #pragma unroll
      for (int r=0;r<16;r++){
        int e = r*512 + tid;
        int b = e >> 7, kk = e & 127;
        int mm = kt*128 + kk;
        float v;
        if (kt < 4)      v = Ech[(size_t)yv[b]*HH + mm];
        else if (kt < 8) v = ctx[b*HH + (mm-512)];
        else             v = hr[b*HH + (mm-1024)];
        sXs[kk*65 + b] = v;
      }
      __syncthreads();
      const float* wrow[8];
      #pragma unroll
      for (int jj=0;jj<8;jj++){
        int j = (jj>>1)*512 + k0 + (jj&1);
        if (kt < 8) wrow[jj] = Wih + (size_t)j*1024 + kt*128;       // [emb; ctx] columns
        else        wrow[jj] = Whh + (size_t)j*512  + (kt-8)*128;
      }
      #pragma unroll
      for (int it=0; it<4; it++){
        int kkb = w*16 + it*4;
        float x0 = sXs[(kkb+0)*65 + lane];
        float x1 = sXs[(kkb+1)*65 + lane];
        float x2 = sXs[(kkb+2)*65 + lane];
        float x3 = sXs[(kkb+3)*65 + lane];
        #pragma unroll
        for (int jj=0;jj<8;jj++){
          float4 wv = *(const float4*)(wrow[jj] + kkb);
          acc[jj] += wv.x*x0; acc[jj] += wv.y*x1;
          acc[jj] += wv.z*x2; acc[jj] += wv.w*x3;
        }
      }
    }
    __syncthreads();
    #pragma unroll
    for (int jj=0;jj<8;jj++) sRed[(w*8+jj)*64 + lane] = acc[jj];
    __syncthreads();
    {
      int jj2 = tid >> 6, b2 = tid & 63;
      int j = (jj2>>1)*512 + k0 + (jj2&1);
      float g = biasf[j];
      #pragma unroll
      for (int w2=0; w2<8; w2++) g += sRed[(w2*8+jj2)*64 + b2];
      sGate[jj2*64 + b2] = g;
    }
    __syncthreads();
    if (tid < 128){
      int k01 = tid >> 6, b3 = tid & 63;
      int k = k0 + k01;
      float gi = sGate[(0+k01)*64 + b3];
      float gf = sGate[(2+k01)*64 + b3];
      float gg = sGate[(4+k01)*64 + b3];
      float go = sGate[(6+k01)*64 + b3];
      float co = cb[b3*HH + k];
      float cn = sigm_(gf)*co + sigm_(gi)*tanhf(gg);
      cb[b3*HH + k] = cn;
      hw[b3*HH + k] = sigm_(go)*tanhf(cn);
    }
  };

  // B: qt[b][h'] = sum_k Wkey[k][h'] * h[b][k]   (b_key cancels in softmax)
  auto phaseB = [&](const float* hw){
    if (bid < 32){
      int hcol = tid;
      int b0 = bid*2, b1 = b0+1;
      const float* hp0 = hw + b0*HH;
      const float* hp1 = hw + b1*HH;
      float a0=0.f, a1=0.f;
      for (int k=0;k<512;k++){
        float wv = Wkey[(size_t)k*512 + hcol];
        a0 += wv * hp0[k];
        a1 += wv * hp1[k];
      }
      qt[b0*HH + hcol] = a0;
      qt[b1*HH + hcol] = a1;
    }
  };

  // C: streaming online-softmax attention over valid rows; per-chunk partials
  auto phaseC = [&](){
    if (tid < 65) sPref[tid] = pref[tid];
    if (tid < 64){ int ln = slen[tid]; if(ln<1)ln=1; if(ln>LL)ln=LL; sLenA[tid]=ln; }
    const int nTot = *nTotP;
    const int w = tid >> 6, lane = tid & 63;
    const float SCALE = 1.0f / sqrtf(512.0f);
    while (true){
      __syncthreads();
      if (tid == 0) sChunk = atomicAdd(cntP, 1);
      __syncthreads();
      int c = sChunk;
      if (c >= nTot) break;
      int b = 0;
      while (sPref[b+1] <= c) b++;
      int slot = c - sPref[b];
      int l0 = slot * CH;
      int lend = min(l0 + CH, sLenA[b]);
      const float4* qp = (const float4*)(qt + b*HH);
      float4 qa = qp[lane], qb = qp[64+lane];
      float m = -FLT_MAX, ss = 0.f;
      float4 aA = make_float4(0,0,0,0), aB = make_float4(0,0,0,0);
      for (int l = l0 + w; l < lend; l += 8){
        const float4* rp = (const float4*)(seq + ((size_t)b*LL + l)*HH);
        float4 ea = rp[lane]; float4 eb = rp[64+lane];
        float d = ea.x*qa.x + ea.y*qa.y + ea.z*qa.z + ea.w*qa.w
                + eb.x*qb.x + eb.y*qb.y + eb.z*qb.z + eb.w*qb.w;
        #pragma unroll
        for (int msk=1; msk<64; msk<<=1) d += __shfl_xor(d, msk, 64);
        float sc = d * SCALE;
        float mn = fmaxf(m, sc);
        float r1 = expf(m - mn);
        float w1 = expf(sc - mn);
        ss = ss*r1 + w1;
        aA.x = aA.x*r1 + w1*ea.x; aA.y = aA.y*r1 + w1*ea.y;
        aA.z = aA.z*r1 + w1*ea.z; aA.w = aA.w*r1 + w1*ea.w;
        aB.x = aB.x*r1 + w1*eb.x; aB.y = aB.y*r1 + w1*eb.y;
        aB.z = aB.z*r1 + w1*eb.z; aB.w = aB.w*r1 + w1*eb.w;
        m = mn;
      }
      ((float4*)(sAcc + w*512))[lane]    = aA;
      ((float4*)(sAcc + w*512))[64+lane] = aB;
      if (lane == 0){ sWm[w] = m; sWs[w] = ss; }
      __syncthreads();
      if (tid == 0){
        float M = sWm[0];
        #pragma unroll
        for (int i=1;i<8;i++) M = fmaxf(M, sWm[i]);
        float S = 0.f;
        #pragma unroll
        for (int i=0;i<8;i++){ float f = expf(sWm[i]-M); sWf[i]=f; S += sWs[i]*f; }
        pm[b*MS+slot] = M; ps[b*MS+slot] = S;
      }
      __syncthreads();
      {
        float v = 0.f;
        #pragma unroll
        for (int i=0;i<8;i++) v += sAcc[i*512 + tid] * sWf[i];
        pacc[((size_t)(b*MS+slot))*HH + tid] = v;
      }
    }
  };

  // D: reduce chunk partials -> ebar; ctx = Wval*ebar + bval; logits; gumbel sample
  auto phaseD = [&](int t, const float* hw){
    if (bid < 64){
      const int b = bid;
      const int nsl = pref[b+1] - pref[b];
      if (tid < nsl){ sAm[tid] = pm[b*MS + tid]; sAs[tid] = ps[b*MS + tid]; }
      __syncthreads();
      if (tid == 0){
        float M = sAm[0];
        for (int s=1;s<nsl;s++) M = fmaxf(M, sAm[s]);
        float S = 0.f;
        for (int s=0;s<nsl;s++){ float f = expf(sAm[s]-M); sAf[s] = f; S += sAs[s]*f; }
        sSc[0] = S;
      }
      __syncthreads();
      {
        float S = sSc[0];
        float v = 0.f;
        for (int s=0;s<nsl;s++) v += pacc[((size_t)(b*MS+s))*HH + tid] * sAf[s];
        sEb[tid] = v / S;
        sHs[tid] = hw[b*HH + tid];
      }
      __syncthreads();
      {
        // ctx[k] = bval[k] + dot(Wval row k, ebar)  — materialized like the reference
        const float4* wr = (const float4*)(Wval + (size_t)tid*HH);
        const float4* er = (const float4*)sEb;
        float a = bval[tid];
        #pragma unroll 4
        for (int i=0;i<HH/4;i++){
          float4 w4 = wr[i], e4 = er[i];
          a += w4.x*e4.x; a += w4.y*e4.y; a += w4.z*e4.z; a += w4.w*e4.w;
        }
        sCt[tid] = a;
        ctx[b*HH + tid] = a;
      }
      __syncthreads();
      if (t >= 0){
        if (tid < 34*8){
          int v = tid >> 3, ks = tid & 7;
          const float* wr = Wcdn + (size_t)v*1024 + ks*128;
          const float* xr = (ks < 4) ? (sHs + ks*128) : (sCt + (ks-4)*128);
          float p = 0.f;
          for (int i=0;i<128;i++) p += wr[i]*xr[i];
          sP[v*8+ks] = p;
        }
        __syncthreads();
        if (tid < 34){
          float lg = bcdn[tid];
          #pragma unroll
          for (int i=0;i<8;i++) lg += sP[tid*8+i];
          // step key = fold_in(key(42), t) = threefry([0,42],[0,t])
          unsigned kk0, kk1; tf2x32_(0u, 42u, 0u, (unsigned)t, kk0, kk1);
          int idx = b*34 + tid;
          unsigned o0, o1, bits;
#if PARTITIONABLE
          tf2x32_(kk0, kk1, 0u, (unsigned)idx, o0, o1);
          bits = o0 ^ o1;
#else
          if (idx < 1088){ tf2x32_(kk0, kk1, (unsigned)idx, (unsigned)(idx+1088), o0, o1); bits = o0; }
          else           { tf2x32_(kk0, kk1, (unsigned)(idx-1088), (unsigned)idx, o0, o1); bits = o1; }
#endif
          float f = __uint_as_float((bits>>9) | 0x3f800000u) - 1.0f;
          float u = fmaxf(f, 1.17549435e-38f);
          float gmb = -logf(-logf(u));
          sZ[tid] = lg + gmb;
        }
        __syncthreads();
        if (tid == 0){
          float best = sZ[0]; int bi = 0;
          for (int v2=1; v2<34; v2++){ if (sZ[v2] > best){ best = sZ[v2]; bi = v2; } }
          yv[b] = bi;
          out[b*TT + t] = bi;
        }
      }
    } else if (bid == 64){
      if (tid == 0) *cntP = 0;   // reset chunk counter for next step's phase C
    }
  };

  // ================= schedule =================
  grid.sync();
  phaseC();                 // qt == 0 -> uniform weights -> ebar0 = mean(e[:len])
  grid.sync();
  phaseD(-1, h0);           // ebar/ctx only, no sampling; resets counter
  grid.sync();
  for (int t = 0; t < TT; t++){
    const float* hr = (t & 1) ? h1 : h0;
    float* hwv      = (t & 1) ? h0 : h1;
    phaseA(hr, hwv);
    grid.sync();
    phaseB(hwv);
    grid.sync();
    phaseC();
    grid.sync();
    phaseD(t, hwv);
    grid.sync();
  }
}

extern "C" void kernel_launch(void* const* d_in, const int* in_sizes, int n_in,
                              void* d_out, int out_size, void* d_ws, size_t ws_size,
                              hipStream_t stream)
{
  const float* seq  = (const float*)d_in[0];
  const int*   slen = (const int*)d_in[1];
  const float* Ech  = (const float*)d_in[2];
  const float* Wkey = (const float*)d_in[3];
  // d_in[4] = b_key: cancels inside softmax (constant over l), unused.
  const float* Wval = (const float*)d_in[5];
  const float* bval = (const float*)d_in[6];
  const float* Wih  = (const float*)d_in[7];
  const float* Whh  = (const float*)d_in[8];
  const float* bih  = (const float*)d_in[9];
  const float* bhh  = (const float*)d_in[10];
  const float* Wcdn = (const float*)d_in[11];
  const float* bcdn = (const float*)d_in[12];
  int*   out = (int*)d_out;
  float* ws  = (float*)d_ws;

  // pick chunk granularity so the partial buffers fit ws_size
  int MS = 32;
  while (MS > 1){
    size_t base = 2048 + 5*(size_t)NB*HH;                 // biasf + h0,h1,cb,ctx,qt
    size_t need = (base + (size_t)NB*MS*(2 + HH))*4 + 1024;
    if (need <= ws_size) break;
    MS >>= 1;
  }
  int CH = 2048 / MS;

  void* args[] = { (void*)&seq, (void*)&slen, (void*)&Ech, (void*)&Wkey,
                   (void*)&Wval, (void*)&bval, (void*)&Wih, (void*)&Whh,
                   (void*)&bih, (void*)&bhh, (void*)&Wcdn, (void*)&bcdn,
                   (void*)&out, (void*)&ws, (void*)&MS, (void*)&CH };
  hipLaunchCooperativeKernel((void*)speller_kernel, dim3(GRID), dim3(BLKT),
                             args, 0, stream);
}

// Round 3
// 116064.099 us; speedup vs baseline: 1.5893x; 1.5893x over previous
//
#include <hip/hip_runtime.h>
#include <cstdint>
#include <cfloat>
#include <cmath>

#define NB 64
#define LL 2048
#define HH 512
#define VV 34
#define TT 600

// JAX threefry_partitionable (default since jax 0.4.36): bits = o0 ^ o1. VERIFIED round 2.
#define PARTITIONABLE 1

__device__ __forceinline__ float sigm_(float x){ return 1.0f/(1.0f+expf(-x)); }
__device__ __forceinline__ unsigned rotl_(unsigned x, int r){ return (x<<r)|(x>>(32-r)); }

// Threefry-2x32, 20 rounds, exactly JAX's schedule.
__device__ __forceinline__ void tf2x32_(unsigned k0, unsigned k1, unsigned x0, unsigned x1,
                                        unsigned &o0, unsigned &o1){
  unsigned ks2 = k0 ^ k1 ^ 0x1BD11BDAu;
  x0 += k0; x1 += k1;
  x0+=x1; x1=rotl_(x1,13); x1^=x0;
  x0+=x1; x1=rotl_(x1,15); x1^=x0;
  x0+=x1; x1=rotl_(x1,26); x1^=x0;
  x0+=x1; x1=rotl_(x1, 6); x1^=x0;
  x0+=k1; x1+=ks2+1u;
  x0+=x1; x1=rotl_(x1,17); x1^=x0;
  x0+=x1; x1=rotl_(x1,29); x1^=x0;
  x0+=x1; x1=rotl_(x1,16); x1^=x0;
  x0+=x1; x1=rotl_(x1,24); x1^=x0;
  x0+=ks2; x1+=k0+2u;
  x0+=x1; x1=rotl_(x1,13); x1^=x0;
  x0+=x1; x1=rotl_(x1,15); x1^=x0;
  x0+=x1; x1=rotl_(x1,26); x1^=x0;
  x0+=x1; x1=rotl_(x1, 6); x1^=x0;
  x0+=k0; x1+=k1+3u;
  x0+=x1; x1=rotl_(x1,17); x1^=x0;
  x0+=x1; x1=rotl_(x1,29); x1^=x0;
  x0+=x1; x1=rotl_(x1,16); x1^=x0;
  x0+=x1; x1=rotl_(x1,24); x1^=x0;
  x0+=k1; x1+=ks2+4u;
  x0+=x1; x1=rotl_(x1,13); x1^=x0;
  x0+=x1; x1=rotl_(x1,15); x1^=x0;
  x0+=x1; x1=rotl_(x1,26); x1^=x0;
  x0+=x1; x1=rotl_(x1, 6); x1^=x0;
  x0+=ks2; x1+=k0+5u;
  o0 = x0; o1 = x1;
}

// ================= P0: one-time init =================
__global__ __launch_bounds__(512) void k_init(
    const int* __restrict__ slen, const float* __restrict__ bih, const float* __restrict__ bhh,
    float* __restrict__ biasf, float* __restrict__ h0, float* __restrict__ h1,
    float* __restrict__ cb, float* __restrict__ qt,
    int* __restrict__ yv, int* __restrict__ pref, int* __restrict__ nTotP,
    int* __restrict__ cntP, int CH)
{
  int gid = blockIdx.x*512 + threadIdx.x;
  if (gid < NB*HH){ h0[gid]=0.f; h1[gid]=0.f; cb[gid]=0.f; qt[gid]=0.f; }
  if (gid < NB) yv[gid] = 0;  // SOS
  if (gid < 2048) biasf[gid] = bih[gid] + bhh[gid];
  if (gid == 0){
    int acc = 0; pref[0] = 0;
    for (int b=0;b<NB;b++){
      int ln = slen[b]; if (ln < 1) ln = 1; if (ln > LL) ln = LL;
      acc += (ln + CH - 1)/CH;
      pref[b+1] = acc;
    }
    *nTotP = acc; *cntP = 0;
  }
}

// ================= A: LSTM gates + state update =================
__global__ __launch_bounds__(512, 2) void k_lstm(
    const float* __restrict__ Ech, const float* __restrict__ Wih, const float* __restrict__ Whh,
    const float* __restrict__ biasf, const int* __restrict__ yv,
    const float* __restrict__ ctx, const float* __restrict__ hr,
    float* __restrict__ hw, float* __restrict__ cb)
{
  const int tid = threadIdx.x;
  const int bid = blockIdx.x;
  __shared__ float sXs[128*65];
  __shared__ float sRed[8*8*64];
  __shared__ float sGate[8*64];

  const int k0 = bid*2;
  const int w = tid >> 6, lane = tid & 63;
  float acc[8];
  #pragma unroll
  for (int jj=0;jj<8;jj++) acc[jj]=0.f;
  for (int kt=0; kt<12; kt++){
    __syncthreads();
    #pragma unroll
    for (int r=0;r<16;r++){
      int e = r*512 + tid;
      int b = e >> 7, kk = e & 127;
      int mm = kt*128 + kk;
      float v;
      if (kt < 4)      v = Ech[(size_t)yv[b]*HH + mm];
      else if (kt < 8) v = ctx[b*HH + (mm-512)];
      else             v = hr[b*HH + (mm-1024)];
      sXs[kk*65 + b] = v;
    }
    __syncthreads();
    const float* wrow[8];
    #pragma unroll
    for (int jj=0;jj<8;jj++){
      int j = (jj>>1)*512 + k0 + (jj&1);
      if (kt < 8) wrow[jj] = Wih + (size_t)j*1024 + kt*128;
      else        wrow[jj] = Whh + (size_t)j*512  + (kt-8)*128;
    }
    #pragma unroll
    for (int it=0; it<4; it++){
      int kkb = w*16 + it*4;
      float x0 = sXs[(kkb+0)*65 + lane];
      float x1 = sXs[(kkb+1)*65 + lane];
      float x2 = sXs[(kkb+2)*65 + lane];
      float x3 = sXs[(kkb+3)*65 + lane];
      #pragma unroll
      for (int jj=0;jj<8;jj++){
        float4 wv = *(const float4*)(wrow[jj] + kkb);
        acc[jj] += wv.x*x0; acc[jj] += wv.y*x1;
        acc[jj] += wv.z*x2; acc[jj] += wv.w*x3;
      }
    }
  }
  __syncthreads();
  #pragma unroll
  for (int jj=0;jj<8;jj++) sRed[(w*8+jj)*64 + lane] = acc[jj];
  __syncthreads();
  {
    int jj2 = tid >> 6, b2 = tid & 63;
    int j = (jj2>>1)*512 + k0 + (jj2&1);
    float g = biasf[j];
    #pragma unroll
    for (int w2=0; w2<8; w2++) g += sRed[(w2*8+jj2)*64 + b2];
    sGate[jj2*64 + b2] = g;
  }
  __syncthreads();
  if (tid < 128){
    int k01 = tid >> 6, b3 = tid & 63;
    int k = k0 + k01;
    float gi = sGate[(0+k01)*64 + b3];
    float gf = sGate[(2+k01)*64 + b3];
    float gg = sGate[(4+k01)*64 + b3];
    float go = sGate[(6+k01)*64 + b3];
    float co = cb[b3*HH + k];
    float cn = sigm_(gf)*co + sigm_(gi)*tanhf(gg);
    cb[b3*HH + k] = cn;
    hw[b3*HH + k] = sigm_(go)*tanhf(cn);
  }
}

// ================= B: qt = Wkey^T h ; block 32 resets chunk counter =================
__global__ __launch_bounds__(512) void k_qt(
    const float* __restrict__ Wkey, const float* __restrict__ hw,
    float* __restrict__ qt, int* __restrict__ cntP)
{
  const int tid = threadIdx.x;
  const int bid = blockIdx.x;
  if (bid == 32){
    if (tid == 0) *cntP = 0;
    return;
  }
  int hcol = tid;
  int b0 = bid*2, b1 = b0+1;
  const float* hp0 = hw + b0*HH;
  const float* hp1 = hw + b1*HH;
  float a0=0.f, a1=0.f;
  for (int k=0;k<512;k++){
    float wv = Wkey[(size_t)k*512 + hcol];
    a0 += wv * hp0[k];
    a1 += wv * hp1[k];
  }
  qt[b0*HH + hcol] = a0;
  qt[b1*HH + hcol] = a1;
}

// ================= C: streaming online-softmax attention =================
__global__ __launch_bounds__(512, 2) void k_attn(
    const float* __restrict__ seq, const int* __restrict__ slen,
    const float* __restrict__ qt, float* __restrict__ pm, float* __restrict__ ps,
    float* __restrict__ pacc, const int* __restrict__ pref,
    const int* __restrict__ nTotP, int* __restrict__ cntP, int MS, int CH)
{
  const int tid = threadIdx.x;
  __shared__ float sAcc[8*512];
  __shared__ float sWm[8], sWs[8], sWf[8];
  __shared__ int   sChunk;
  __shared__ int   sPref[65];
  __shared__ int   sLenA[64];

  if (tid < 65) sPref[tid] = pref[tid];
  if (tid < 64){ int ln = slen[tid]; if(ln<1)ln=1; if(ln>LL)ln=LL; sLenA[tid]=ln; }
  const int nTot = *nTotP;
  const int w = tid >> 6, lane = tid & 63;
  const float SCALE = 1.0f / sqrtf(512.0f);
  while (true){
    __syncthreads();
    if (tid == 0) sChunk = atomicAdd(cntP, 1);
    __syncthreads();
    int c = sChunk;
    if (c >= nTot) break;
    int b = 0;
    while (sPref[b+1] <= c) b++;
    int slot = c - sPref[b];
    int l0 = slot * CH;
    int lend = min(l0 + CH, sLenA[b]);
    const float4* qp = (const float4*)(qt + b*HH);
    float4 qa = qp[lane], qb = qp[64+lane];
    float m = -FLT_MAX, ss = 0.f;
    float4 aA = make_float4(0,0,0,0), aB = make_float4(0,0,0,0);
    int l = l0 + w;
    float4 ea, eb;
    if (l < lend){
      const float4* rp = (const float4*)(seq + ((size_t)b*LL + l)*HH);
      ea = rp[lane]; eb = rp[64+lane];
    }
    while (l < lend){
      int ln2 = l + 8;
      float4 na, nb;
      if (ln2 < lend){   // prefetch next row (no arithmetic reorder)
        const float4* rp2 = (const float4*)(seq + ((size_t)b*LL + ln2)*HH);
        na = rp2[lane]; nb = rp2[64+lane];
      }
      float d = ea.x*qa.x + ea.y*qa.y + ea.z*qa.z + ea.w*qa.w
              + eb.x*qb.x + eb.y*qb.y + eb.z*qb.z + eb.w*qb.w;
      #pragma unroll
      for (int msk=1; msk<64; msk<<=1) d += __shfl_xor(d, msk, 64);
      float sc = d * SCALE;
      float mn = fmaxf(m, sc);
      float r1 = expf(m - mn);
      float w1 = expf(sc - mn);
      ss = ss*r1 + w1;
      aA.x = aA.x*r1 + w1*ea.x; aA.y = aA.y*r1 + w1*ea.y;
      aA.z = aA.z*r1 + w1*ea.z; aA.w = aA.w*r1 + w1*ea.w;
      aB.x = aB.x*r1 + w1*eb.x; aB.y = aB.y*r1 + w1*eb.y;
      aB.z = aB.z*r1 + w1*eb.z; aB.w = aB.w*r1 + w1*eb.w;
      m = mn;
      ea = na; eb = nb; l = ln2;
    }
    ((float4*)(sAcc + w*512))[lane]    = aA;
    ((float4*)(sAcc + w*512))[64+lane] = aB;
    if (lane == 0){ sWm[w] = m; sWs[w] = ss; }
    __syncthreads();
    if (tid == 0){
      float M = sWm[0];
      #pragma unroll
      for (int i=1;i<8;i++) M = fmaxf(M, sWm[i]);
      float S = 0.f;
      #pragma unroll
      for (int i=0;i<8;i++){ float f = expf(sWm[i]-M); sWf[i]=f; S += sWs[i]*f; }
      pm[b*MS+slot] = M; ps[b*MS+slot] = S;
    }
    __syncthreads();
    {
      float v = 0.f;
      #pragma unroll
      for (int i=0;i<8;i++) v += sAcc[i*512 + tid] * sWf[i];
      pacc[((size_t)(b*MS+slot))*HH + tid] = v;
    }
  }
}

// ================= D: reduce -> ebar -> ctx ; logits ; gumbel sample =================
__global__ __launch_bounds__(512) void k_ctx(
    const float* __restrict__ Wval, const float* __restrict__ bval,
    const float* __restrict__ Wcdn, const float* __restrict__ bcdn,
    const float* __restrict__ hw, const float* __restrict__ pm, const float* __restrict__ ps,
    const float* __restrict__ pacc, const int* __restrict__ pref,
    float* __restrict__ ctx, int* __restrict__ yv, int* __restrict__ out,
    int MS, int t)
{
  const int tid = threadIdx.x;
  const int b = blockIdx.x;
  __shared__ float sEb[512];
  __shared__ float sHs[512];
  __shared__ float sCt[512];
  __shared__ float sP[34*8];
  __shared__ float sZ[34];
  __shared__ float sAm[32], sAs[32], sAf[32];
  __shared__ float sSc[2];

  const int nsl = pref[b+1] - pref[b];
  if (tid < nsl){ sAm[tid] = pm[b*MS + tid]; sAs[tid] = ps[b*MS + tid]; }
  __syncthreads();
  if (tid == 0){
    float M = sAm[0];
    for (int s=1;s<nsl;s++) M = fmaxf(M, sAm[s]);
    float S = 0.f;
    for (int s=0;s<nsl;s++){ float f = expf(sAm[s]-M); sAf[s] = f; S += sAs[s]*f; }
    sSc[0] = S;
  }
  __syncthreads();
  {
    float S = sSc[0];
    float v = 0.f;
    for (int s=0;s<nsl;s++) v += pacc[((size_t)(b*MS+s))*HH + tid] * sAf[s];
    sEb[tid] = v / S;
    sHs[tid] = hw[b*HH + tid];
  }
  __syncthreads();
  {
    const float4* wr = (const float4*)(Wval + (size_t)tid*HH);
    const float4* er = (const float4*)sEb;
    float a = bval[tid];
    #pragma unroll 4
    for (int i=0;i<HH/4;i++){
      float4 w4 = wr[i], e4 = er[i];
      a += w4.x*e4.x; a += w4.y*e4.y; a += w4.z*e4.z; a += w4.w*e4.w;
    }
    sCt[tid] = a;
    ctx[b*HH + tid] = a;
  }
  __syncthreads();
  if (t >= 0){
    if (tid < 34*8){
      int v = tid >> 3, ks = tid & 7;
      const float* wr = Wcdn + (size_t)v*1024 + ks*128;
      const float* xr = (ks < 4) ? (sHs + ks*128) : (sCt + (ks-4)*128);
      float p = 0.f;
      for (int i=0;i<128;i++) p += wr[i]*xr[i];
      sP[v*8+ks] = p;
    }
    __syncthreads();
    if (tid < 34){
      float lg = bcdn[tid];
      #pragma unroll
      for (int i=0;i<8;i++) lg += sP[tid*8+i];
      unsigned kk0, kk1; tf2x32_(0u, 42u, 0u, (unsigned)t, kk0, kk1);
      int idx = b*34 + tid;
      unsigned o0, o1, bits;
#if PARTITIONABLE
      tf2x32_(kk0, kk1, 0u, (unsigned)idx, o0, o1);
      bits = o0 ^ o1;
#else
      if (idx < 1088){ tf2x32_(kk0, kk1, (unsigned)idx, (unsigned)(idx+1088), o0, o1); bits = o0; }
      else           { tf2x32_(kk0, kk1, (unsigned)(idx-1088), (unsigned)idx, o0, o1); bits = o1; }
#endif
      float f = __uint_as_float((bits>>9) | 0x3f800000u) - 1.0f;
      float u = fmaxf(f, 1.17549435e-38f);
      float gmb = -logf(-logf(u));
      sZ[tid] = lg + gmb;
    }
    __syncthreads();
    if (tid == 0){
      float best = sZ[0]; int bi = 0;
      for (int v2=1; v2<34; v2++){ if (sZ[v2] > best){ best = sZ[v2]; bi = v2; } }
      yv[b] = bi;
      out[b*TT + t] = bi;
    }
  }
}

extern "C" void kernel_launch(void* const* d_in, const int* in_sizes, int n_in,
                              void* d_out, int out_size, void* d_ws, size_t ws_size,
                              hipStream_t stream)
{
  const float* seq  = (const float*)d_in[0];
  const int*   slen = (const int*)d_in[1];
  const float* Ech  = (const float*)d_in[2];
  const float* Wkey = (const float*)d_in[3];
  // d_in[4] = b_key: cancels inside softmax (constant over l), unused.
  const float* Wval = (const float*)d_in[5];
  const float* bval = (const float*)d_in[6];
  const float* Wih  = (const float*)d_in[7];
  const float* Whh  = (const float*)d_in[8];
  const float* bih  = (const float*)d_in[9];
  const float* bhh  = (const float*)d_in[10];
  const float* Wcdn = (const float*)d_in[11];
  const float* bcdn = (const float*)d_in[12];
  int*   out = (int*)d_out;
  float* ws  = (float*)d_ws;

  // pick chunk granularity so the partial buffers fit ws_size
  int MS = 32;
  while (MS > 1){
    size_t base = 2048 + 5*(size_t)NB*HH;                 // biasf + h0,h1,cb,ctx,qt
    size_t need = (base + (size_t)NB*MS*(2 + HH))*4 + 1024;
    if (need <= ws_size) break;
    MS >>= 1;
  }
  int CH = 2048 / MS;

  // ---- workspace layout (identical to verified round-2 kernel) ----
  float* biasf = ws;
  float* h0    = biasf + 2048;
  float* h1    = h0 + NB*HH;
  float* cb    = h1 + NB*HH;
  float* ctx   = cb + NB*HH;
  float* qt    = ctx + NB*HH;
  float* pm    = qt + NB*HH;
  float* ps    = pm + NB*MS;
  float* pacc  = ps + NB*MS;
  int*   iw    = (int*)(pacc + (size_t)NB*MS*HH);
  int*   yv    = iw;
  int*   pref  = iw + 64;
  int*   nTotP = iw + 129;
  int*   cntP  = iw + 130;

  k_init<<<256, 512, 0, stream>>>(slen, bih, bhh, biasf, h0, h1, cb, qt,
                                  yv, pref, nTotP, cntP, CH);
  // initial context: qt==0 -> uniform weights over valid positions
  k_attn<<<256, 512, 0, stream>>>(seq, slen, qt, pm, ps, pacc, pref, nTotP, cntP, MS, CH);
  k_ctx<<<64, 512, 0, stream>>>(Wval, bval, Wcdn, bcdn, h0, pm, ps, pacc, pref,
                                ctx, yv, out, MS, -1);
  for (int t = 0; t < TT; t++){
    const float* hr = (t & 1) ? h1 : h0;
    float* hw       = (t & 1) ? h0 : h1;
    k_lstm<<<256, 512, 0, stream>>>(Ech, Wih, Whh, biasf, yv, ctx, hr, hw, cb);
    k_qt<<<33, 512, 0, stream>>>(Wkey, hw, qt, cntP);   // block 32 resets chunk counter
    k_attn<<<256, 512, 0, stream>>>(seq, slen, qt, pm, ps, pacc, pref, nTotP, cntP, MS, CH);
    k_ctx<<<64, 512, 0, stream>>>(Wval, bval, Wcdn, bcdn, hw, pm, ps, pacc, pref,
                                  ctx, yv, out, MS, t);
  }
}